// Round 17
// baseline (955.820 us; speedup 1.0000x reference)
//
#include <hip/hip_runtime.h>
#include <hip/hip_bf16.h>
#include <stdint.h>

#define NPER 4096
#define NCLOUD 8
#define FD 64
#define SS 1024
#define NBK 64
#define CAP 512

typedef unsigned int u32;
typedef unsigned long long u64;
typedef __attribute__((ext_vector_type(8))) short short8v;      // 8 bf16 (4 VGPR) MFMA frag
typedef __attribute__((ext_vector_type(8))) unsigned short ushort8v;
typedef __attribute__((ext_vector_type(4))) float f32x4;        // MFMA acc frag

// ---- exact fp32 helpers (no FMA contraction; must match numpy reference) ----
__device__ __forceinline__ float fadd(float a, float b){ return __fadd_rn(a,b); }
__device__ __forceinline__ float fsub(float a, float b){ return __fsub_rn(a,b); }
__device__ __forceinline__ float fmul(float a, float b){ return __fmul_rn(a,b); }
__device__ __forceinline__ float dist2(float ax,float ay,float az,float bx,float by,float bz){
  float dx=fsub(ax,bx), dy=fsub(ay,by), dz=fsub(az,bz);
  return fadd(fadd(fmul(dx,dx),fmul(dy,dy)),fmul(dz,dz));
}
__device__ __forceinline__ unsigned short f2b(float v){
  __hip_bfloat16 h = __float2bfloat16(v);   // RNE
  return *reinterpret_cast<unsigned short*>(&h);
}

// ---- DPP helpers: row_ror:N = 0x120|N, row_bcast15 = 0x142, row_bcast31 = 0x143
template<int CTRL, int RMASK>
__device__ __forceinline__ float dppmaxf(float v){
  int t = __builtin_amdgcn_update_dpp(0, __float_as_int(v), CTRL, RMASK, 0xf, false);
  return fmaxf(v, __int_as_float(t));   // masked lanes get old=0; d2>=0 so harmless
}
// u64-min butterfly stage; old = -1 so masked-row lanes are no-ops for min
template<int CTRL, int RMASK>
__device__ __forceinline__ void kmin_stage(u32& hi, u32& lo){
  u32 hio = (u32)__builtin_amdgcn_update_dpp(-1, (int)hi, CTRL, RMASK, 0xf, false);
  u32 loo = (u32)__builtin_amdgcn_update_dpp(-1, (int)lo, CTRL, RMASK, 0xf, false);
  u64 ko = ((u64)hio<<32)|loo, k = ((u64)hi<<32)|lo;
  bool g = ko < k;
  hi = g?hio:hi; lo = g?loo:lo;
}

// ============================================================================
// Kernel 1: FPS — r11 EXACTLY (best measured; structural plateau ~838cy issue
// + ~590cy sync/latency per iter at 1 wave/SIMD). Tie-breaks bit-exact.
// ============================================================================
#define LOADG(q, j0, j1, j2, j3) { \
    const float4* pv = (const float4*)(pb + (size_t)(base + q*4)*3); \
    float4 v0=pv[0], v1=pv[1], v2=pv[2]; \
    x##j0=v0.x; y##j0=v0.y; z##j0=v0.z; \
    x##j1=v0.w; y##j1=v1.x; z##j1=v1.y; \
    x##j2=v1.z; y##j2=v1.w; z##j2=v2.x; \
    x##j3=v2.y; y##j3=v2.z; z##j3=v2.w; \
    float4 c0; c0.x=x##j0; c0.y=y##j0; c0.z=z##j0; c0.w=0.f; spt[base+q*4+0]=c0; \
    float4 c1; c1.x=x##j1; c1.y=y##j1; c1.z=z##j1; c1.w=0.f; spt[base+q*4+1]=c1; \
    float4 c2; c2.x=x##j2; c2.y=y##j2; c2.z=z##j2; c2.w=0.f; spt[base+q*4+2]=c2; \
    float4 c3; c3.x=x##j3; c3.y=y##j3; c3.z=z##j3; c3.w=0.f; spt[base+q*4+3]=c3; \
  }
#define DINIT(j) m##j = dist2(x##j,y##j,z##j,p0x,p0y,p0z);
#define DUPD(j)  { float d = dist2(x##j,y##j,z##j,pnx,pny,pnz); m##j = fminf(m##j,d); }
#define ARGMAX16() { \
      bool c; float w0,w1,w2,w3,w4,w5,w6,w7; int i0,i1,i2,i3,i4,i5,i6,i7; \
      c=m1>m0;   w0=c?m1:m0;   i0=base+(c?1:0); \
      c=m3>m2;   w1=c?m3:m2;   i1=base+(c?3:2); \
      c=m5>m4;   w2=c?m5:m4;   i2=base+(c?5:4); \
      c=m7>m6;   w3=c?m7:m6;   i3=base+(c?7:6); \
      c=m9>m8;   w4=c?m9:m8;   i4=base+(c?9:8); \
      c=m11>m10; w5=c?m11:m10; i5=base+(c?11:10); \
      c=m13>m12; w6=c?m13:m12; i6=base+(c?13:12); \
      c=m15>m14; w7=c?m15:m14; i7=base+(c?15:14); \
      c=w1>w0; w0=c?w1:w0; i0=c?i1:i0; \
      c=w3>w2; w2=c?w3:w2; i2=c?i3:i2; \
      c=w5>w4; w4=c?w5:w4; i4=c?i5:i4; \
      c=w7>w6; w6=c?w7:w6; i6=c?i7:i6; \
      c=w2>w0; w0=c?w2:w0; i0=c?i2:i0; \
      c=w6>w4; w4=c?w6:w4; i4=c?i6:i4; \
      c=w4>w0; bv=c?w4:w0; bidx=c?i4:i0; \
    }
#define FPS_ITER(IT, WX, WY, WZ) { \
    float rv = bv; \
    rv = dppmaxf<0x121,0xf>(rv); \
    rv = dppmaxf<0x122,0xf>(rv); \
    rv = dppmaxf<0x124,0xf>(rv); \
    rv = dppmaxf<0x128,0xf>(rv); \
    rv = dppmaxf<0x142,0xa>(rv); \
    rv = dppmaxf<0x143,0xc>(rv); \
    const float wv = __int_as_float(__builtin_amdgcn_readlane(__float_as_int(rv), 63)); \
    u64 em = __ballot(bv == wv); \
    const int wl = __ffsll(em) - 1; \
    const int par = (IT) & 1; \
    if (lane == wl) \
      skey[par][w] = ((u64)__float_as_uint(wv)<<32) | (u64)(u32)(4095 - bidx); \
    __syncthreads(); \
    const u64* kp = &skey[par][0]; \
    u64 k0=kp[0], k1=kp[1], k2=kp[2], k3=kp[3]; \
    u64 ka = k0>k1?k0:k1, kb2 = k2>k3?k2:k3; \
    u64 km = ka>kb2?ka:kb2; \
    const int nxt = 4095 - (int)(km & 0xFFFull); \
    const float4 c = spt[nxt]; \
    const float pnx = __int_as_float(__builtin_amdgcn_readfirstlane(__float_as_int(c.x))); \
    const float pny = __int_as_float(__builtin_amdgcn_readfirstlane(__float_as_int(c.y))); \
    const float pnz = __int_as_float(__builtin_amdgcn_readfirstlane(__float_as_int(c.z))); \
    const bool mine = (t == ((IT) & 255)); \
    WX = mine ? pnx : WX; \
    WY = mine ? pny : WY; \
    WZ = mine ? pnz : WZ; \
    DUPD(0) DUPD(1) DUPD(2) DUPD(3) DUPD(4) DUPD(5) DUPD(6) DUPD(7) \
    DUPD(8) DUPD(9) DUPD(10) DUPD(11) DUPD(12) DUPD(13) DUPD(14) DUPD(15) \
    ARGMAX16() \
  }

__global__ __launch_bounds__(256, 1) void k_fps(const float* __restrict__ pos,
    float* __restrict__ pos_s, float* __restrict__ out_pos1, float* __restrict__ out_b1){
  __shared__ __align__(16) float4 spt[NPER];   // point table, 64KB, b128 broadcast
  __shared__ __align__(16) u64 skey[2][4];     // per-wave winner keys, parity-buffered
  const int b = blockIdx.x;
  const int t = threadIdx.x;
  const int w = t >> 6, lane = t & 63;
  const float* pb = pos + (size_t)b*NPER*3;
  const int base = t*16;
  float x0,x1,x2,x3,x4,x5,x6,x7,x8,x9,x10,x11,x12,x13,x14,x15;
  float y0,y1,y2,y3,y4,y5,y6,y7,y8,y9,y10,y11,y12,y13,y14,y15;
  float z0,z1,z2,z3,z4,z5,z6,z7,z8,z9,z10,z11,z12,z13,z14,z15;
  float m0,m1,m2,m3,m4,m5,m6,m7,m8,m9,m10,m11,m12,m13,m14,m15;
  LOADG(0, 0, 1, 2, 3)
  LOADG(1, 4, 5, 6, 7)
  LOADG(2, 8, 9, 10, 11)
  LOADG(3, 12, 13, 14, 15)
  const float p0x=pb[0], p0y=pb[1], p0z=pb[2];
  DINIT(0) DINIT(1) DINIT(2) DINIT(3) DINIT(4) DINIT(5) DINIT(6) DINIT(7)
  DINIT(8) DINIT(9) DINIT(10) DINIT(11) DINIT(12) DINIT(13) DINIT(14) DINIT(15)
  float bv; int bidx;
  ARGMAX16()
  float wx0=p0x, wy0=p0y, wz0=p0z;
  float wx1=0.f, wy1=0.f, wz1=0.f;
  float wx2=0.f, wy2=0.f, wz2=0.f;
  float wx3=0.f, wy3=0.f, wz3=0.f;
  for (int i=t;i<SS;i+=256) out_b1[b*SS+i] = (float)b;
  __syncthreads();   // drains init stores once; loop below has NO global ops
  for (int it=1;   it<256;  ++it) FPS_ITER(it, wx0, wy0, wz0)
  for (int it=256; it<512;  ++it) FPS_ITER(it, wx1, wy1, wz1)
  for (int it=512; it<768;  ++it) FPS_ITER(it, wx2, wy2, wz2)
  for (int it=768; it<1024; ++it) FPS_ITER(it, wx3, wy3, wz3)
  {
    const size_t g = (size_t)b*SS;
    size_t o = (g + t)*3;
    pos_s[o]=wx0; pos_s[o+1]=wy0; pos_s[o+2]=wz0;
    out_pos1[o]=wx0; out_pos1[o+1]=wy0; out_pos1[o+2]=wz0;
    o = (g + 256 + t)*3;
    pos_s[o]=wx1; pos_s[o+1]=wy1; pos_s[o+2]=wz1;
    out_pos1[o]=wx1; out_pos1[o+1]=wy1; out_pos1[o+2]=wz1;
    o = (g + 512 + t)*3;
    pos_s[o]=wx2; pos_s[o+1]=wy2; pos_s[o+2]=wz2;
    out_pos1[o]=wx2; out_pos1[o+1]=wy2; out_pos1[o+2]=wz2;
    o = (g + 768 + t)*3;
    pos_s[o]=wx3; pos_s[o+1]=wy3; pos_s[o+2]=wz3;
    out_pos1[o]=wx3; out_pos1[o+1]=wy3; out_pos1[o+2]=wz3;
  }
}

// ============================================================================
// Kernel 2: weight pre-convert (standalone, launched FIRST — independent of
// FPS; r14 proved co-residency with k_fps costs ~40us, so keep it separate).
// ============================================================================
__global__ __launch_bounds__(256) void k_wconv(const float* __restrict__ W1,
    const float* __restrict__ W2, const float* __restrict__ W3,
    unsigned short* __restrict__ Wt1, unsigned short* __restrict__ Wt2,
    unsigned short* __restrict__ Wt3){
  int t = blockIdx.x*256 + threadIdx.x;
  if (t < 16384){
    int n = t>>7, k = t&127;
    Wt1[t] = f2b(k < 67 ? W1[k*128+n] : 0.f);
  } else if (t < 32768){
    int q = t - 16384; int n = q>>7, k = q&127;
    Wt2[q] = f2b(W2[k*128+n]);
  } else if (t < 65536){
    int q = t - 32768; int n = q>>7, k = q&127;
    Wt3[q] = f2b(W3[k*256+n]);
  }
}

// ============================================================================
// Kernel 3: FUSED radius-kNN + edge-MLP + masked max. 512 thr, 4 samples/blk,
// 2048 blocks. Removes the device-wide nbr->mlp sync, one launch, and the
// 1MB nbr global round-trip: each block searches neighbors for ITS samples
// (phase A) then MLPs them (phase B). LDS overlay: positions(48K)+lst(16K)
// occupy exactly hbuf's 64K region; wbuf(64K) persists across phases (Wt1
// staged by waves 4-7 DURING selection by waves 0-3). Neighbor candidate
// SET is order-independent (consumer is a permutation-invariant max), so the
// 2-wave-per-sample scan's nondeterministic append order is harmless; keys
// (d2<<12|idx) are absolute => selected 64-set bit-exact vs top_k.
// ============================================================================
__device__ __forceinline__ u64 wave_min_u64(u64 k){
  u32 hi = (u32)(k>>32), lo = (u32)k;
  kmin_stage<0x121,0xf>(hi,lo);
  kmin_stage<0x122,0xf>(hi,lo);
  kmin_stage<0x124,0xf>(hi,lo);
  kmin_stage<0x128,0xf>(hi,lo);
  kmin_stage<0x142,0xa>(hi,lo);   // row_bcast15 -> rows 1,3
  kmin_stage<0x143,0xc>(hi,lo);   // row_bcast31 -> rows 2,3
  u32 rhi = (u32)__builtin_amdgcn_readlane((int)hi, 63);
  u32 rlo = (u32)__builtin_amdgcn_readlane((int)lo, 63);
  return ((u64)rhi<<32) | rlo;
}

__device__ __forceinline__ void load_w256(const unsigned short* __restrict__ src,
    unsigned short* __restrict__ wb, int tt){       // tt in [0,256): rows 0-127
  const int n = tt>>1, hf = tt&1;
  const char* srow = (const char*)(src + n*128 + hf*64);
  char* drow = (char*)wb + n*256;
  const u32 sw = (u32)(n&7)<<4;
  #pragma unroll
  for (int c=0;c<8;c++){
    ushort8v v = *(const ushort8v*)(srow + c*16);
    u32 colbyte = (u32)hf*128 + (u32)c*16;
    *(ushort8v*)(drow + (colbyte ^ sw)) = v;
  }
}

__device__ __forceinline__ void load_w512(const unsigned short* __restrict__ src,
    unsigned short* __restrict__ wb, int t){        // 512 thr cover 128 rows
  const int n = t>>2, q = t&3;
  const char* srow = (const char*)(src + n*128 + q*32);
  char* drow = (char*)wb + n*256;
  const u32 sw = (u32)(n&7)<<4;
  #pragma unroll
  for (int c=0;c<4;c++){
    ushort8v v = *(const ushort8v*)(srow + c*16);
    u32 colbyte = (u32)q*64 + (u32)c*16;
    *(ushort8v*)(drow + (colbyte ^ sw)) = v;
  }
}

__device__ __forceinline__ void load_w3full(const unsigned short* __restrict__ src,
    unsigned short* __restrict__ wb, int t){        // 512 thr cover 256 rows
  const int n = t>>1, hf = t&1;
  const char* srow = (const char*)(src + n*128 + hf*64);
  char* drow = (char*)wb + n*256;
  const u32 sw = (u32)(n&7)<<4;
  #pragma unroll
  for (int c=0;c<8;c++){
    ushort8v v = *(const ushort8v*)(srow + c*16);
    u32 colbyte = (u32)hf*128 + (u32)c*16;
    *(ushort8v*)(drow + (colbyte ^ sw)) = v;
  }
}

__device__ __forceinline__ void zero_acc(f32x4 acc[4][4]){
  #pragma unroll
  for (int i=0;i<4;i++){
    #pragma unroll
    for (int j=0;j<4;j++){
      f32x4 z = {0.f,0.f,0.f,0.f};
      acc[i][j] = z;
    }
  }
}

__device__ __forceinline__ void gemm_wave(const unsigned short* __restrict__ wb,
    const unsigned short* __restrict__ hb, int rbase, int nh, int lane, int ksteps,
    f32x4 acc[4][4]){
  const int li = lane & 15;
  const int lg = lane >> 4;
  for (int kk=0; kk<ksteps; ++kk){
    const u32 colb = (u32)(kk*64 + lg*16);
    short8v af[4], bfv[4];
    #pragma unroll
    for (int mt=0;mt<4;mt++){
      int wr = rbase + nh*64 + mt*16 + li;
      af[mt] = *(const short8v*)((const char*)wb + wr*256 + (colb ^ ((u32)(wr&7)<<4)));
    }
    #pragma unroll
    for (int nt=0;nt<4;nt++){
      int er = nt*16 + li;
      bfv[nt] = *(const short8v*)((const char*)hb + er*256 + (colb ^ ((u32)(er&7)<<4)));
    }
    #pragma unroll
    for (int mt=0;mt<4;mt++){
      #pragma unroll
      for (int nt=0;nt<4;nt++){
        acc[mt][nt] = __builtin_amdgcn_mfma_f32_16x16x32_bf16(af[mt], bfv[nt], acc[mt][nt], 0, 0, 0);
      }
    }
  }
}

__device__ __forceinline__ void epi_store(f32x4 acc[4][4], const float* __restrict__ bias,
    unsigned short* __restrict__ hb, int nh, int lane){
  const int li = lane & 15;
  const int lg = lane >> 4;
  #pragma unroll
  for (int mt=0;mt<4;mt++){
    const int c0 = nh*64 + mt*16 + lg*4;
    const float4 bb = *(const float4*)(bias + c0);
    #pragma unroll
    for (int nt=0;nt<4;nt++){
      const int r = nt*16 + li;
      f32x4 a = acc[mt][nt];
      float v0 = fmaxf(a.x + bb.x, 0.f);
      float v1 = fmaxf(a.y + bb.y, 0.f);
      float v2 = fmaxf(a.z + bb.z, 0.f);
      float v3 = fmaxf(a.w + bb.w, 0.f);
      u64 pk = (u64)f2b(v0) | ((u64)f2b(v1)<<16) | ((u64)f2b(v2)<<32) | ((u64)f2b(v3)<<48);
      u32 colbyte = (u32)(c0*2);
      *(u64*)((char*)hb + r*256 + (colbyte ^ ((u32)(r&7)<<4))) = pk;
    }
  }
}

__device__ __forceinline__ void epi_out(f32x4 acc[4][4], const float* __restrict__ b3g,
    float* __restrict__ outx, u64 vmask, int pass, int nh, int lane, int gs){
  const int li = lane & 15;
  const int lg = lane >> 4;
  #pragma unroll
  for (int mt=0;mt<4;mt++){
    const int c0 = pass*128 + nh*64 + mt*16 + lg*4;
    const float4 bb = *(const float4*)(b3g + c0);
    float vals[4];
    #pragma unroll
    for (int i=0;i<4;i++){
      float v = -1e30f;
      #pragma unroll
      for (int nt=0;nt<4;nt++){
        const int r = nt*16 + li;
        const bool ok = (vmask >> r) & 1ull;
        const float a = acc[mt][nt][i];
        v = fmaxf(v, ok ? a : -1e30f);
      }
      #pragma unroll
      for (int off=1; off<16; off<<=1){
        v = fmaxf(v, __shfl_xor(v, off, 64));
      }
      float biasv = (i==0)?bb.x:((i==1)?bb.y:((i==2)?bb.z:bb.w));
      vals[i] = fmaxf(v + biasv, 0.f);   // relu(max+bias) == max(relu(row+bias))
    }
    if (li==0){
      float4 o; o.x=vals[0]; o.y=vals[1]; o.z=vals[2]; o.w=vals[3];
      *(float4*)(outx + (size_t)gs*256 + c0) = o;
    }
  }
}

__global__ __launch_bounds__(512) void k_fused(const float* __restrict__ xg,
    const float* __restrict__ pg, const float* __restrict__ pos_s,
    const unsigned short* __restrict__ Wt1, const unsigned short* __restrict__ Wt2,
    const unsigned short* __restrict__ Wt3,
    const float* __restrict__ b1g, const float* __restrict__ b2g,
    const float* __restrict__ b3g, float* __restrict__ outx){
  __shared__ __align__(16) unsigned char smem[131072];  // 64K hbuf-region + 64K wbuf
  __shared__ float spos[4][4];
  __shared__ unsigned short snbr_l[4][64];
  __shared__ u64 svalid[4];
  __shared__ int cnt[4];
  // overlay pointers
  float* sxx = (float*)smem;                       // [0,16K)
  float* syy = sxx + NPER;                         // [16K,32K)
  float* szz = syy + NPER;                         // [32K,48K)
  u64*   lst = (u64*)(smem + 49152);               // [48K,64K): [4][512] u64
  unsigned short* hbuf = (unsigned short*)smem;    // phase B: [0,64K)
  unsigned short* wbuf = (unsigned short*)(smem + 65536);  // [64K,128K), persists
  const int t = threadIdx.x;
  const int w = t>>6, lane = t&63;
  const int s0 = blockIdx.x*4;
  const int b = s0 >> 10;
  // ================= PHASE A: neighbor search =================
  {
    const float* pb = pg + (size_t)b*NPER*3;
    for (int i=t;i<NPER;i+=512){
      sxx[i]=pb[i*3+0]; syy[i]=pb[i*3+1]; szz[i]=pb[i*3+2];
    }
    if (t<4){
      cnt[t]=0;
      spos[t][0]=pos_s[(size_t)(s0+t)*3+0];
      spos[t][1]=pos_s[(size_t)(s0+t)*3+1];
      spos[t][2]=pos_s[(size_t)(s0+t)*3+2];
    }
    __syncthreads();
    const int s = w & 3, half = w >> 2;            // 2 waves per sample
    const int gid = s0 + s;
    const float qx=pos_s[(size_t)gid*3+0], qy=pos_s[(size_t)gid*3+1], qz=pos_s[(size_t)gid*3+2];
    u64* ls = lst + (size_t)s*CAP;
    const int p0 = half*2048;
    for (int i0=p0;i0<p0+2048;i0+=64){
      int p = i0 + lane;
      float d = dist2(qx,qy,qz,sxx[p],syy[p],szz[p]);
      bool in = (d <= 0.04f);                      // f32(RADIUS**2) == 0.04f
      u64 m = __ballot(in);
      if (m){
        int tot = __popcll(m);
        int bse = 0;
        if (lane==0) bse = atomicAdd(&cnt[s], tot);
        bse = __shfl(bse, 0, 64);
        if (in){
          int o = bse + __popcll(m & ((1ull<<lane)-1ull));
          if (o < CAP) ls[o] = ((u64)__float_as_uint(d)<<12) | (u64)(u32)p;
        }
      }
    }
    __syncthreads();
    if (w < 4){
      // selection for sample w (keys absolute -> set bit-exact vs top_k)
      const int s2 = w;
      u64* l2 = lst + (size_t)s2*CAP;
      int n = cnt[s2];
      if (n > CAP) n = CAP;   // mean ~137; P(>512) ~ 0
      unsigned short outv = 0xFFFFu;
      if (n <= 64){
        if (lane < n) outv = (unsigned short)(l2[lane] & 0xFFFull);
      } else if (n <= 256){
        u64 c0=~0ull, c1=~0ull, c2=~0ull, c3=~0ull;
        c0 = l2[lane];
        if (lane+64  < n) c1 = l2[lane+64];
        if (lane+128 < n) c2 = l2[lane+128];
        if (lane+192 < n) c3 = l2[lane+192];
        for (int r=0;r<64;++r){
          u64 a  = c0<c1?c0:c1; int ia = c0<c1?0:1;
          u64 b2 = c2<c3?c2:c3; int ib = c2<c3?2:3;
          u64 bk = a<b2?a:b2;   int bp = a<b2?ia:ib;
          u64 rk = wave_min_u64(bk);
          if (bk == rk){
            if (bp==0) c0=~0ull; else if (bp==1) c1=~0ull;
            else if (bp==2) c2=~0ull; else c3=~0ull;
          }
          if (lane == r) outv = (unsigned short)(rk & 0xFFFull);
        }
      } else {
        for (int r=0;r<64;++r){
          u64 bk = ~0ull; int bp = -1;
          for (int i=lane;i<n;i+=64){
            u64 v = l2[i];
            bool lt = v < bk;
            bk = lt ? v : bk;
            bp = lt ? i : bp;
          }
          u64 rk = wave_min_u64(bk);
          if (bk == rk) l2[bp] = ~0ull;
          if (lane == r) outv = (unsigned short)(rk & 0xFFFull);
        }
      }
      snbr_l[s2][lane] = outv;
      u64 vm = __ballot(outv != 0xFFFFu);
      if (lane==0) svalid[s2] = vm;
    } else {
      load_w256(Wt1, wbuf, t - 256);   // stage Wt1 during selection (overlap)
    }
    __syncthreads();   // phase A done: snbr/svalid/wbuf ready; pos/lst dead
  }
  // ================= PHASE B: edge-MLP + masked max =================
  {
    u64* p = (u64*)hbuf;   // zero E buffer (8192 u64 / 512 thr)
    #pragma unroll
    for (int i=0;i<16;i++) p[t + i*512] = 0ull;
  }
  __syncthreads();
  { // gather: thread -> (sample s=t>>7, neighbor-row r, feature-half hf)
    const int s = t>>7, r=(t>>1)&63, hf=t&1;
    const unsigned short nb = snbr_l[s][r];
    char* drow = (char*)hbuf + (s*64+r)*256;
    const u32 sw = (u32)(r&7)<<4;
    if (nb != 0xFFFFu){
      const float4* xr = (const float4*)(xg + ((size_t)b*NPER + nb)*FD + hf*32);
      #pragma unroll
      for (int c=0;c<4;c++){
        float4 v0 = xr[2*c];
        float4 v1 = xr[2*c+1];
        ushort8v u;
        u[0]=f2b(v0.x); u[1]=f2b(v0.y); u[2]=f2b(v0.z); u[3]=f2b(v0.w);
        u[4]=f2b(v1.x); u[5]=f2b(v1.y); u[6]=f2b(v1.z); u[7]=f2b(v1.w);
        u32 colbyte = (u32)hf*64 + (u32)c*16;
        *(ushort8v*)(drow + (colbyte ^ sw)) = u;
      }
      if (hf){ // rel pos -> cols 64..66 (col 67 zero)
        const size_t po = ((size_t)b*NPER + nb)*3;
        float rx = fsub(pg[po+0], spos[s][0]);
        float ry = fsub(pg[po+1], spos[s][1]);
        float rz = fsub(pg[po+2], spos[s][2]);
        u64 pk = (u64)f2b(rx) | ((u64)f2b(ry)<<16) | ((u64)f2b(rz)<<32);
        *(u64*)(drow + (128u ^ sw)) = pk;
      }
    }
  }
  __syncthreads();
  const int s = w>>1, nh = w&1;     // 8 waves: 4 samples x 2 col-halves
  unsigned short* hb = hbuf + (size_t)s*64*128;
  f32x4 acc[4][4];
  zero_acc(acc);
  gemm_wave(wbuf, hb, 0, nh, lane, 3, acc);       // L1: K=96 (Wt1 pre-staged)
  __syncthreads();
  epi_store(acc, b1g, hb, nh, lane);              // h1 over E (reads done)
  load_w512(Wt2, wbuf, t);
  __syncthreads();
  zero_acc(acc);
  gemm_wave(wbuf, hb, 0, nh, lane, 4, acc);       // L2: K=128
  __syncthreads();
  epi_store(acc, b2g, hb, nh, lane);              // h2 over h1
  load_w3full(Wt3, wbuf, t);                      // ALL 256 W3 rows, once
  __syncthreads();
  const u64 vm = svalid[s];
  zero_acc(acc);
  gemm_wave(wbuf, hb, 0,   nh, lane, 4, acc);     // L3 pass 0 (out cols 0-127)
  epi_out(acc, b3g, outx, vm, 0, nh, lane, s0+s);
  zero_acc(acc);
  gemm_wave(wbuf, hb, 128, nh, lane, 4, acc);     // L3 pass 1 (out cols 128-255)
  epi_out(acc, b3g, outx, vm, 1, nh, lane, s0+s);
}

// ============================================================================
extern "C" void kernel_launch(void* const* d_in, const int* in_sizes, int n_in,
                              void* d_out, int out_size, void* d_ws, size_t ws_size,
                              hipStream_t stream) {
  (void)in_sizes; (void)n_in; (void)out_size; (void)ws_size;
  const float* xg = (const float*)d_in[0];
  const float* pg = (const float*)d_in[1];
  const float* W1 = (const float*)d_in[3];
  const float* b1 = (const float*)d_in[4];
  const float* W2 = (const float*)d_in[5];
  const float* b2 = (const float*)d_in[6];
  const float* W3 = (const float*)d_in[7];
  const float* b3 = (const float*)d_in[8];
  float* outx = (float*)d_out;                       // [8192,256]
  float* outp = outx + (size_t)8192*256;             // [8192,3]
  float* outb = outp + (size_t)8192*3;               // [8192]
  char* ws = (char*)d_ws;
  float* pos_s = (float*)ws;                                      // 98304 B
  unsigned short* Wt1 = (unsigned short*)(ws + 98304 + 1048576);  // 32 KB
  unsigned short* Wt2 = Wt1 + 16384;                              // 32 KB
  unsigned short* Wt3 = Wt2 + 16384;                              // 64 KB
  hipLaunchKernelGGL(k_wconv, dim3(256), dim3(256), 0, stream, W1, W2, W3, Wt1, Wt2, Wt3);
  hipLaunchKernelGGL(k_fps, dim3(NCLOUD), dim3(256), 0, stream, pg, pos_s, outp, outb);
  hipLaunchKernelGGL(k_fused, dim3(8192/4), dim3(512), 0, stream,
                     xg, pg, pos_s, Wt1, Wt2, Wt3, b1, b2, b3, outx);
}

// Round 18
// 895.787 us; speedup vs baseline: 1.0670x; 1.0670x over previous
//
#include <hip/hip_runtime.h>
#include <hip/hip_bf16.h>
#include <stdint.h>

#define NPER 4096
#define NCLOUD 8
#define FD 64
#define SS 1024
#define NBK 64
#define CAP 512

typedef unsigned int u32;
typedef unsigned long long u64;
typedef __attribute__((ext_vector_type(8))) short short8v;      // 8 bf16 (4 VGPR) MFMA frag
typedef __attribute__((ext_vector_type(8))) unsigned short ushort8v;
typedef __attribute__((ext_vector_type(4))) float f32x4;        // MFMA acc frag

// ---- exact fp32 helpers (no FMA contraction; must match numpy reference) ----
__device__ __forceinline__ float fadd(float a, float b){ return __fadd_rn(a,b); }
__device__ __forceinline__ float fsub(float a, float b){ return __fsub_rn(a,b); }
__device__ __forceinline__ float fmul(float a, float b){ return __fmul_rn(a,b); }
__device__ __forceinline__ float dist2(float ax,float ay,float az,float bx,float by,float bz){
  float dx=fsub(ax,bx), dy=fsub(ay,by), dz=fsub(az,bz);
  return fadd(fadd(fmul(dx,dx),fmul(dy,dy)),fmul(dz,dz));
}
__device__ __forceinline__ unsigned short f2b(float v){
  __hip_bfloat16 h = __float2bfloat16(v);   // RNE
  return *reinterpret_cast<unsigned short*>(&h);
}

// ---- DPP helpers: row_ror:N = 0x120|N, row_bcast15 = 0x142, row_bcast31 = 0x143
template<int CTRL, int RMASK>
__device__ __forceinline__ float dppmaxf(float v){
  int t = __builtin_amdgcn_update_dpp(0, __float_as_int(v), CTRL, RMASK, 0xf, false);
  return fmaxf(v, __int_as_float(t));   // masked lanes get old=0; d2>=0 so harmless
}
// u64-min butterfly stage; old = -1 so masked-row lanes are no-ops for min
template<int CTRL, int RMASK>
__device__ __forceinline__ void kmin_stage(u32& hi, u32& lo){
  u32 hio = (u32)__builtin_amdgcn_update_dpp(-1, (int)hi, CTRL, RMASK, 0xf, false);
  u32 loo = (u32)__builtin_amdgcn_update_dpp(-1, (int)lo, CTRL, RMASK, 0xf, false);
  u64 ko = ((u64)hio<<32)|loo, k = ((u64)hi<<32)|lo;
  bool g = ko < k;
  hi = g?hio:hi; lo = g?loo:lo;
}

// ============================================================================
// Kernel 1: FPS — r11 EXACTLY (structural plateau: ~838cy issue + ~590cy
// barrier/LDS latency per iter at W=1 wave/SIMD; 608-648us across builds,
// the spread being co-compiled-codegen noise). Tie-breaks bit-exact vs
// jnp.argmax: strict-> tree (lower idx wins), ballot lowest lane = lowest
// global idx, key = val<<32 | (4095-idx) u64 max.
// ============================================================================
#define LOADG(q, j0, j1, j2, j3) { \
    const float4* pv = (const float4*)(pb + (size_t)(base + q*4)*3); \
    float4 v0=pv[0], v1=pv[1], v2=pv[2]; \
    x##j0=v0.x; y##j0=v0.y; z##j0=v0.z; \
    x##j1=v0.w; y##j1=v1.x; z##j1=v1.y; \
    x##j2=v1.z; y##j2=v1.w; z##j2=v2.x; \
    x##j3=v2.y; y##j3=v2.z; z##j3=v2.w; \
    float4 c0; c0.x=x##j0; c0.y=y##j0; c0.z=z##j0; c0.w=0.f; spt[base+q*4+0]=c0; \
    float4 c1; c1.x=x##j1; c1.y=y##j1; c1.z=z##j1; c1.w=0.f; spt[base+q*4+1]=c1; \
    float4 c2; c2.x=x##j2; c2.y=y##j2; c2.z=z##j2; c2.w=0.f; spt[base+q*4+2]=c2; \
    float4 c3; c3.x=x##j3; c3.y=y##j3; c3.z=z##j3; c3.w=0.f; spt[base+q*4+3]=c3; \
  }
#define DINIT(j) m##j = dist2(x##j,y##j,z##j,p0x,p0y,p0z);
#define DUPD(j)  { float d = dist2(x##j,y##j,z##j,pnx,pny,pnz); m##j = fminf(m##j,d); }
#define ARGMAX16() { \
      bool c; float w0,w1,w2,w3,w4,w5,w6,w7; int i0,i1,i2,i3,i4,i5,i6,i7; \
      c=m1>m0;   w0=c?m1:m0;   i0=base+(c?1:0); \
      c=m3>m2;   w1=c?m3:m2;   i1=base+(c?3:2); \
      c=m5>m4;   w2=c?m5:m4;   i2=base+(c?5:4); \
      c=m7>m6;   w3=c?m7:m6;   i3=base+(c?7:6); \
      c=m9>m8;   w4=c?m9:m8;   i4=base+(c?9:8); \
      c=m11>m10; w5=c?m11:m10; i5=base+(c?11:10); \
      c=m13>m12; w6=c?m13:m12; i6=base+(c?13:12); \
      c=m15>m14; w7=c?m15:m14; i7=base+(c?15:14); \
      c=w1>w0; w0=c?w1:w0; i0=c?i1:i0; \
      c=w3>w2; w2=c?w3:w2; i2=c?i3:i2; \
      c=w5>w4; w4=c?w5:w4; i4=c?i5:i4; \
      c=w7>w6; w6=c?w7:w6; i6=c?i7:i6; \
      c=w2>w0; w0=c?w2:w0; i0=c?i2:i0; \
      c=w6>w4; w4=c?w6:w4; i4=c?i6:i4; \
      c=w4>w0; bv=c?w4:w0; bidx=c?i4:i0; \
    }
#define FPS_ITER(IT, WX, WY, WZ) { \
    float rv = bv; \
    rv = dppmaxf<0x121,0xf>(rv); \
    rv = dppmaxf<0x122,0xf>(rv); \
    rv = dppmaxf<0x124,0xf>(rv); \
    rv = dppmaxf<0x128,0xf>(rv); \
    rv = dppmaxf<0x142,0xa>(rv); \
    rv = dppmaxf<0x143,0xc>(rv); \
    const float wv = __int_as_float(__builtin_amdgcn_readlane(__float_as_int(rv), 63)); \
    u64 em = __ballot(bv == wv); \
    const int wl = __ffsll(em) - 1; \
    const int par = (IT) & 1; \
    if (lane == wl) \
      skey[par][w] = ((u64)__float_as_uint(wv)<<32) | (u64)(u32)(4095 - bidx); \
    __syncthreads(); \
    const u64* kp = &skey[par][0]; \
    u64 k0=kp[0], k1=kp[1], k2=kp[2], k3=kp[3]; \
    u64 ka = k0>k1?k0:k1, kb2 = k2>k3?k2:k3; \
    u64 km = ka>kb2?ka:kb2; \
    const int nxt = 4095 - (int)(km & 0xFFFull); \
    const float4 c = spt[nxt]; \
    const float pnx = __int_as_float(__builtin_amdgcn_readfirstlane(__float_as_int(c.x))); \
    const float pny = __int_as_float(__builtin_amdgcn_readfirstlane(__float_as_int(c.y))); \
    const float pnz = __int_as_float(__builtin_amdgcn_readfirstlane(__float_as_int(c.z))); \
    const bool mine = (t == ((IT) & 255)); \
    WX = mine ? pnx : WX; \
    WY = mine ? pny : WY; \
    WZ = mine ? pnz : WZ; \
    DUPD(0) DUPD(1) DUPD(2) DUPD(3) DUPD(4) DUPD(5) DUPD(6) DUPD(7) \
    DUPD(8) DUPD(9) DUPD(10) DUPD(11) DUPD(12) DUPD(13) DUPD(14) DUPD(15) \
    ARGMAX16() \
  }

__global__ __launch_bounds__(256, 1) void k_fps(const float* __restrict__ pos,
    float* __restrict__ pos_s, float* __restrict__ out_pos1, float* __restrict__ out_b1){
  __shared__ __align__(16) float4 spt[NPER];   // point table, 64KB, b128 broadcast
  __shared__ __align__(16) u64 skey[2][4];     // per-wave winner keys, parity-buffered
  const int b = blockIdx.x;
  const int t = threadIdx.x;
  const int w = t >> 6, lane = t & 63;
  const float* pb = pos + (size_t)b*NPER*3;
  const int base = t*16;
  float x0,x1,x2,x3,x4,x5,x6,x7,x8,x9,x10,x11,x12,x13,x14,x15;
  float y0,y1,y2,y3,y4,y5,y6,y7,y8,y9,y10,y11,y12,y13,y14,y15;
  float z0,z1,z2,z3,z4,z5,z6,z7,z8,z9,z10,z11,z12,z13,z14,z15;
  float m0,m1,m2,m3,m4,m5,m6,m7,m8,m9,m10,m11,m12,m13,m14,m15;
  LOADG(0, 0, 1, 2, 3)
  LOADG(1, 4, 5, 6, 7)
  LOADG(2, 8, 9, 10, 11)
  LOADG(3, 12, 13, 14, 15)
  const float p0x=pb[0], p0y=pb[1], p0z=pb[2];
  DINIT(0) DINIT(1) DINIT(2) DINIT(3) DINIT(4) DINIT(5) DINIT(6) DINIT(7)
  DINIT(8) DINIT(9) DINIT(10) DINIT(11) DINIT(12) DINIT(13) DINIT(14) DINIT(15)
  float bv; int bidx;
  ARGMAX16()
  float wx0=p0x, wy0=p0y, wz0=p0z;
  float wx1=0.f, wy1=0.f, wz1=0.f;
  float wx2=0.f, wy2=0.f, wz2=0.f;
  float wx3=0.f, wy3=0.f, wz3=0.f;
  for (int i=t;i<SS;i+=256) out_b1[b*SS+i] = (float)b;
  __syncthreads();   // drains init stores once; loop below has NO global ops
  for (int it=1;   it<256;  ++it) FPS_ITER(it, wx0, wy0, wz0)
  for (int it=256; it<512;  ++it) FPS_ITER(it, wx1, wy1, wz1)
  for (int it=512; it<768;  ++it) FPS_ITER(it, wx2, wy2, wz2)
  for (int it=768; it<1024; ++it) FPS_ITER(it, wx3, wy3, wz3)
  {
    const size_t g = (size_t)b*SS;
    size_t o = (g + t)*3;
    pos_s[o]=wx0; pos_s[o+1]=wy0; pos_s[o+2]=wz0;
    out_pos1[o]=wx0; out_pos1[o+1]=wy0; out_pos1[o+2]=wz0;
    o = (g + 256 + t)*3;
    pos_s[o]=wx1; pos_s[o+1]=wy1; pos_s[o+2]=wz1;
    out_pos1[o]=wx1; out_pos1[o+1]=wy1; out_pos1[o+2]=wz1;
    o = (g + 512 + t)*3;
    pos_s[o]=wx2; pos_s[o+1]=wy2; pos_s[o+2]=wz2;
    out_pos1[o]=wx2; out_pos1[o+1]=wy2; out_pos1[o+2]=wz2;
    o = (g + 768 + t)*3;
    pos_s[o]=wx3; pos_s[o+1]=wy3; pos_s[o+2]=wz3;
    out_pos1[o]=wx3; out_pos1[o+1]=wy3; out_pos1[o+2]=wz3;
  }
}

// ============================================================================
// Kernel 2: radius kNN (blocks < 2048) + weight pre-convert (blocks >= 2048).
// wconv fused into the throughput kernel (no serial-path interference).
// Selection: register-resident + DPP u64-min butterfly.
// ============================================================================
__device__ __forceinline__ u64 wave_min_u64(u64 k){
  u32 hi = (u32)(k>>32), lo = (u32)k;
  kmin_stage<0x121,0xf>(hi,lo);
  kmin_stage<0x122,0xf>(hi,lo);
  kmin_stage<0x124,0xf>(hi,lo);
  kmin_stage<0x128,0xf>(hi,lo);
  kmin_stage<0x142,0xa>(hi,lo);   // row_bcast15 -> rows 1,3
  kmin_stage<0x143,0xc>(hi,lo);   // row_bcast31 -> rows 2,3
  u32 rhi = (u32)__builtin_amdgcn_readlane((int)hi, 63);
  u32 rlo = (u32)__builtin_amdgcn_readlane((int)lo, 63);
  return ((u64)rhi<<32) | rlo;
}

__global__ __launch_bounds__(256) void k_nbr(const float* __restrict__ pos,
    const float* __restrict__ pos_s, unsigned short* __restrict__ nbr,
    const float* __restrict__ W1, const float* __restrict__ W2, const float* __restrict__ W3,
    unsigned short* __restrict__ Wt1, unsigned short* __restrict__ Wt2,
    unsigned short* __restrict__ Wt3){
  if (blockIdx.x >= 2048){
    int tt = (int)(blockIdx.x - 2048)*256 + (int)threadIdx.x;
    if (tt < 16384){
      int n = tt>>7, k = tt&127;
      Wt1[tt] = f2b(k < 67 ? W1[k*128+n] : 0.f);
    } else if (tt < 32768){
      int q = tt - 16384; int n = q>>7, k = q&127;
      Wt2[q] = f2b(W2[k*128+n]);
    } else if (tt < 65536){
      int q = tt - 32768; int n = q>>7, k = q&127;
      Wt3[q] = f2b(W3[k*256+n]);
    }
    return;
  }
  __shared__ float sxx[NPER], syy[NPER], szz[NPER];
  __shared__ u64 lst[4][CAP];
  __shared__ int cnt[4];
  const int t = threadIdx.x;
  const int w = t>>6, lane = t&63;
  const int gid0 = blockIdx.x*4;
  const int b = gid0 >> 10;
  const float* pb = pos + (size_t)b*NPER*3;
  for (int i=t;i<NPER;i+=256){
    sxx[i]=pb[i*3+0]; syy[i]=pb[i*3+1]; szz[i]=pb[i*3+2];
  }
  if (t<4) cnt[t]=0;
  __syncthreads();
  const int gid = gid0 + w;
  const float qx=pos_s[(size_t)gid*3+0], qy=pos_s[(size_t)gid*3+1], qz=pos_s[(size_t)gid*3+2];
  for (int i0=0;i0<NPER;i0+=64){
    int p = i0 + lane;
    float d = dist2(qx,qy,qz,sxx[p],syy[p],szz[p]);
    bool in = (d <= 0.04f);                   // f32(RADIUS**2) == 0.04f
    u64 m = __ballot(in);
    if (m){
      int tot = __popcll(m);
      int bse = 0;
      if (lane==0) bse = atomicAdd(&cnt[w], tot);
      bse = __shfl(bse, 0, 64);
      if (in){
        int o = bse + __popcll(m & ((1ull<<lane)-1ull));
        if (o < CAP) lst[w][o] = ((u64)__float_as_uint(d)<<12) | (u64)(u32)p;
      }
    }
  }
  int n = cnt[w];
  if (n > CAP) n = CAP;   // mean in-radius count ~137; P(>512) ~ 0
  unsigned short outv = 0xFFFFu;
  if (n <= 64){
    if (lane < n) outv = (unsigned short)(lst[w][lane] & 0xFFFull);
  } else if (n <= 256){
    u64 c0=~0ull, c1=~0ull, c2=~0ull, c3=~0ull;
    c0 = lst[w][lane];
    if (lane+64  < n) c1 = lst[w][lane+64];
    if (lane+128 < n) c2 = lst[w][lane+128];
    if (lane+192 < n) c3 = lst[w][lane+192];
    for (int r=0;r<64;++r){
      u64 a  = c0<c1?c0:c1; int ia = c0<c1?0:1;
      u64 b2 = c2<c3?c2:c3; int ib = c2<c3?2:3;
      u64 bk = a<b2?a:b2;   int bp = a<b2?ia:ib;
      u64 rk = wave_min_u64(bk);
      if (bk == rk){
        if (bp==0) c0=~0ull; else if (bp==1) c1=~0ull;
        else if (bp==2) c2=~0ull; else c3=~0ull;
      }
      if (lane == r) outv = (unsigned short)(rk & 0xFFFull);
    }
  } else {
    for (int r=0;r<64;++r){
      u64 bk = ~0ull; int bp = -1;
      for (int i=lane;i<n;i+=64){
        u64 v = lst[w][i];
        bool lt = v < bk;
        bk = lt ? v : bk;
        bp = lt ? i : bp;
      }
      u64 rk = bk;
      #pragma unroll
      for (int off=32; off>=1; off>>=1){
        u64 o = __shfl_xor(rk, off, 64);
        rk = (o < rk) ? o : rk;
      }
      if (bk == rk) lst[w][bp] = ~0ull;
      if (lane == r) outv = (unsigned short)(rk & 0xFFFull);
    }
  }
  nbr[(size_t)gid*NBK + lane] = outv;
}

// ============================================================================
// Kernel 3: fused edge-MLP + masked max — 512 thr, 4 samples/block, 8 waves
// (s = w>>1, nh = w&1). Weight staging amortized over 4 samples; per-sample
// barrier count halved vs the 2-sample form. LDS 96.6KB -> 1 block/CU.
// ============================================================================
__device__ __forceinline__ void load_w512(const unsigned short* __restrict__ src,
    unsigned short* __restrict__ wb, int t){
  const int n = t>>2, q = t&3;                 // 512 thr: row n, quarter q
  const char* srow = (const char*)(src + n*128 + q*32);
  char* drow = (char*)wb + n*256;
  const u32 sw = (u32)(n&7)<<4;
  #pragma unroll
  for (int c=0;c<4;c++){
    ushort8v v = *(const ushort8v*)(srow + c*16);
    u32 colbyte = (u32)q*64 + (u32)c*16;
    *(ushort8v*)(drow + (colbyte ^ sw)) = v;
  }
}

__device__ __forceinline__ void zero_acc(f32x4 acc[4][4]){
  #pragma unroll
  for (int i=0;i<4;i++){
    #pragma unroll
    for (int j=0;j<4;j++){
      f32x4 z = {0.f,0.f,0.f,0.f};
      acc[i][j] = z;
    }
  }
}

__device__ __forceinline__ void gemm_wave(const unsigned short* __restrict__ wb,
    const unsigned short* __restrict__ hb, int nh, int lane, int ksteps, f32x4 acc[4][4]){
  const int li = lane & 15;
  const int lg = lane >> 4;
  for (int kk=0; kk<ksteps; ++kk){
    const u32 colb = (u32)(kk*64 + lg*16);
    short8v af[4], bfv[4];
    #pragma unroll
    for (int mt=0;mt<4;mt++){
      int wr = nh*64 + mt*16 + li;
      af[mt] = *(const short8v*)((const char*)wb + wr*256 + (colb ^ ((u32)(wr&7)<<4)));
    }
    #pragma unroll
    for (int nt=0;nt<4;nt++){
      int er = nt*16 + li;
      bfv[nt] = *(const short8v*)((const char*)hb + er*256 + (colb ^ ((u32)(er&7)<<4)));
    }
    #pragma unroll
    for (int mt=0;mt<4;mt++){
      #pragma unroll
      for (int nt=0;nt<4;nt++){
        acc[mt][nt] = __builtin_amdgcn_mfma_f32_16x16x32_bf16(af[mt], bfv[nt], acc[mt][nt], 0, 0, 0);
      }
    }
  }
}

__device__ __forceinline__ void epi_store(f32x4 acc[4][4], const float* __restrict__ bias,
    unsigned short* __restrict__ hb, int nh, int lane){
  const int li = lane & 15;
  const int lg = lane >> 4;
  #pragma unroll
  for (int mt=0;mt<4;mt++){
    const int c0 = nh*64 + mt*16 + lg*4;
    const float4 bb = *(const float4*)(bias + c0);
    #pragma unroll
    for (int nt=0;nt<4;nt++){
      const int r = nt*16 + li;
      f32x4 a = acc[mt][nt];
      float v0 = fmaxf(a.x + bb.x, 0.f);
      float v1 = fmaxf(a.y + bb.y, 0.f);
      float v2 = fmaxf(a.z + bb.z, 0.f);
      float v3 = fmaxf(a.w + bb.w, 0.f);
      u64 pk = (u64)f2b(v0) | ((u64)f2b(v1)<<16) | ((u64)f2b(v2)<<32) | ((u64)f2b(v3)<<48);
      u32 colbyte = (u32)(c0*2);
      *(u64*)((char*)hb + r*256 + (colbyte ^ ((u32)(r&7)<<4))) = pk;
    }
  }
}

__device__ __forceinline__ void epi_out(f32x4 acc[4][4], const float* __restrict__ b3g,
    float* __restrict__ outx, u64 vmask, int pass, int nh, int lane, int gs){
  const int li = lane & 15;
  const int lg = lane >> 4;
  #pragma unroll
  for (int mt=0;mt<4;mt++){
    const int c0 = pass*128 + nh*64 + mt*16 + lg*4;
    const float4 bb = *(const float4*)(b3g + c0);
    float vals[4];
    #pragma unroll
    for (int i=0;i<4;i++){
      float v = -1e30f;
      #pragma unroll
      for (int nt=0;nt<4;nt++){
        const int r = nt*16 + li;
        const bool ok = (vmask >> r) & 1ull;
        const float a = acc[mt][nt][i];
        v = fmaxf(v, ok ? a : -1e30f);
      }
      #pragma unroll
      for (int off=1; off<16; off<<=1){
        v = fmaxf(v, __shfl_xor(v, off, 64));
      }
      float biasv = (i==0)?bb.x:((i==1)?bb.y:((i==2)?bb.z:bb.w));
      vals[i] = fmaxf(v + biasv, 0.f);   // relu(max+bias) == max(relu(row+bias))
    }
    if (li==0){
      float4 o; o.x=vals[0]; o.y=vals[1]; o.z=vals[2]; o.w=vals[3];
      *(float4*)(outx + (size_t)gs*256 + c0) = o;
    }
  }
}

__global__ __launch_bounds__(512) void k_mlp(const float* __restrict__ xg,
    const float* __restrict__ pg, const float* __restrict__ pos_s,
    const unsigned short* __restrict__ nbrg,
    const unsigned short* __restrict__ Wt1, const unsigned short* __restrict__ Wt2,
    const unsigned short* __restrict__ Wt3,
    const float* __restrict__ b1g, const float* __restrict__ b2g,
    const float* __restrict__ b3g, float* __restrict__ outx){
  __shared__ __align__(16) unsigned short hbuf[4][64][128];  // E/h in-place, 64KB
  __shared__ __align__(16) unsigned short wbuf[128*128];     // weight tile, 32KB
  __shared__ float spos[4][4];
  __shared__ unsigned short snbr[4][64];
  __shared__ u64 svalid[4];
  const int t = threadIdx.x;
  const int s0 = blockIdx.x*4;
  const int b = s0 >> 10;
  {
    u64* p = (u64*)hbuf;   // 8192 u64 / 512 thr = 16 each
    #pragma unroll
    for (int i=0;i<16;i++) p[t + i*512] = 0ull;
  }
  if (t < 4){
    spos[t][0]=pos_s[(size_t)(s0+t)*3+0];
    spos[t][1]=pos_s[(size_t)(s0+t)*3+1];
    spos[t][2]=pos_s[(size_t)(s0+t)*3+2];
  }
  if (t < 256){
    const int s=t>>6, r=t&63;
    unsigned short nb = nbrg[(size_t)(s0+s)*NBK + r];
    snbr[s][r]=nb;
    u64 m = __ballot(nb != 0xFFFFu);
    if (r==0) svalid[s]=m;
  }
  __syncthreads();
  { // gather: thread -> (sample s=t>>7, neighbor-row r, feature-half hf)
    const int s = t>>7, r=(t>>1)&63, hf=t&1;
    const unsigned short nb = snbr[s][r];
    char* drow = (char*)hbuf + (s*64+r)*256;
    const u32 sw = (u32)(r&7)<<4;
    if (nb != 0xFFFFu){
      const float4* xr = (const float4*)(xg + ((size_t)b*NPER + nb)*FD + hf*32);
      #pragma unroll
      for (int c=0;c<4;c++){
        float4 v0 = xr[2*c];
        float4 v1 = xr[2*c+1];
        ushort8v u;
        u[0]=f2b(v0.x); u[1]=f2b(v0.y); u[2]=f2b(v0.z); u[3]=f2b(v0.w);
        u[4]=f2b(v1.x); u[5]=f2b(v1.y); u[6]=f2b(v1.z); u[7]=f2b(v1.w);
        u32 colbyte = (u32)hf*64 + (u32)c*16;
        *(ushort8v*)(drow + (colbyte ^ sw)) = u;
      }
      if (hf){ // rel pos -> cols 64..66 (col 67 zero)
        const size_t po = ((size_t)b*NPER + nb)*3;
        float rx = fsub(pg[po+0], spos[s][0]);
        float ry = fsub(pg[po+1], spos[s][1]);
        float rz = fsub(pg[po+2], spos[s][2]);
        u64 pk = (u64)f2b(rx) | ((u64)f2b(ry)<<16) | ((u64)f2b(rz)<<32);
        *(u64*)(drow + (128u ^ sw)) = pk;
      }
    }
  }
  load_w512(Wt1, wbuf, t);
  __syncthreads();
  const int w = t>>6, lane = t&63;
  const int s = w>>1, nh = w&1;     // 8 waves: 4 samples x 2 col-halves
  unsigned short* hb = &hbuf[s][0][0];
  f32x4 acc[4][4];
  zero_acc(acc);
  gemm_wave(wbuf, hb, nh, lane, 3, acc);          // L1: K=96 (67 + zero pad)
  __syncthreads();
  epi_store(acc, b1g, hb, nh, lane);              // h1 over E (reads done)
  load_w512(Wt2, wbuf, t);
  __syncthreads();
  zero_acc(acc);
  gemm_wave(wbuf, hb, nh, lane, 4, acc);          // L2: K=128
  __syncthreads();
  epi_store(acc, b2g, hb, nh, lane);              // h2 over h1
  load_w512(Wt3, wbuf, t);                        // W3 cols 0..127
  __syncthreads();
  zero_acc(acc);
  gemm_wave(wbuf, hb, nh, lane, 4, acc);          // L3 pass 0
  const u64 vm = svalid[s];
  epi_out(acc, b3g, outx, vm, 0, nh, lane, s0+s);
  __syncthreads();
  load_w512(Wt3 + 128*128, wbuf, t);              // W3 cols 128..255
  __syncthreads();
  zero_acc(acc);
  gemm_wave(wbuf, hb, nh, lane, 4, acc);          // L3 pass 1
  epi_out(acc, b3g, outx, vm, 1, nh, lane, s0+s);
}

// ============================================================================
extern "C" void kernel_launch(void* const* d_in, const int* in_sizes, int n_in,
                              void* d_out, int out_size, void* d_ws, size_t ws_size,
                              hipStream_t stream) {
  (void)in_sizes; (void)n_in; (void)out_size; (void)ws_size;
  const float* xg = (const float*)d_in[0];
  const float* pg = (const float*)d_in[1];
  const float* W1 = (const float*)d_in[3];
  const float* b1 = (const float*)d_in[4];
  const float* W2 = (const float*)d_in[5];
  const float* b2 = (const float*)d_in[6];
  const float* W3 = (const float*)d_in[7];
  const float* b3 = (const float*)d_in[8];
  float* outx = (float*)d_out;                       // [8192,256]
  float* outp = outx + (size_t)8192*256;             // [8192,3]
  float* outb = outp + (size_t)8192*3;               // [8192]
  char* ws = (char*)d_ws;                            // needs ~1.25 MB
  float* pos_s = (float*)ws;                                      // 98304 B
  unsigned short* nbr = (unsigned short*)(ws + 98304);            // 1 MB
  unsigned short* Wt1 = (unsigned short*)(ws + 98304 + 1048576);  // 32 KB
  unsigned short* Wt2 = Wt1 + 16384;                              // 32 KB
  unsigned short* Wt3 = Wt2 + 16384;                              // 64 KB
  hipLaunchKernelGGL(k_fps, dim3(NCLOUD), dim3(256), 0, stream, pg, pos_s, outp, outb);
  hipLaunchKernelGGL(k_nbr, dim3(2048 + 256), dim3(256), 0, stream,
                     pg, pos_s, nbr, W1, W2, W3, Wt1, Wt2, Wt3);
  hipLaunchKernelGGL(k_mlp, dim3(8192/4), dim3(512), 0, stream,
                     xg, pg, pos_s, nbr, Wt1, Wt2, Wt3, b1, b2, b3, outx);
}